// Round 12
// baseline (201.345 us; speedup 1.0000x reference)
//
#include <hip/hip_runtime.h>
#include <hip/hip_bf16.h>

// out[b, d] = sum_k sc[b,k] * dict[serp(d), k]    B=262144, K=32, D=900.
//
// R11 post-mortem: zero-vmem steady loop helped (202->194) but 1 block/CU
// leaves ~875 cyc/tile of store-idle: prologue (x4 rounds), barrier
// convergence, and compute stretches pause the CU's ONLY store stream.
// Store-bound floor is 138us; we're at 194.
// R12: 2 blocks/CU x zero-vmem steady loop (R9's occupancy + R11's clean
// loop, never yet tested together without the vmcnt hazard). Single 57.6KB
// staging buffer per block (2 x 57.6 = 115.2KB LDS). When block A is in
// compute/barrier, block B's copy feeds the store queue; block n+1's
// prologue hides under block n's steady state. bb[8]=32 + df[15]=60 VGPR
// ~= 160 total < 256 cap of launch_bounds(256,2) -- no squeeze-spill.

typedef __attribute__((ext_vector_type(8))) short bf16x8;
typedef __attribute__((ext_vector_type(4))) float f32x4;

constexpr int KD    = 32;
constexpr int DDIM  = 900;
constexpr int SDIM  = 30;
constexpr int NCHT  = 57;              // 16-col chunks (57*16 = 912)
constexpr int TROWS = 16;              // rows per tile (= MFMA n)
constexpr int TILES = 8;               // tiles per block
constexpr int RPB   = TROWS * TILES;   // 128 rows per block -> 2048 blocks
constexpr int TFL   = TROWS * DDIM;    // 14400 floats staging

__device__ __forceinline__ int serp_src(int d) {
    int r = d / SDIM, c = d - r * SDIM;
    return (r & 1) ? (r * SDIM + (SDIM - 1 - c)) : d;
}

__device__ __forceinline__ short f2bf(float x) {
    __hip_bfloat16 h = __float2bfloat16(x);   // RNE
    short u; __builtin_memcpy(&u, &h, 2); return u;
}

// Barrier ordering LDS only: waits own ds ops, does NOT drain global stores.
__device__ __forceinline__ void barrier_lds() {
    __builtin_amdgcn_sched_barrier(0);
    asm volatile("s_waitcnt lgkmcnt(0)" ::: "memory");
    __builtin_amdgcn_sched_barrier(0);
    __builtin_amdgcn_s_barrier();
    __builtin_amdgcn_sched_barrier(0);
}

__global__ __launch_bounds__(256, 2) void mfma_decode(
    const float* __restrict__ sc,     // [B, 32]
    const float* __restrict__ dict,   // [900, 32]
    float* __restrict__ out,          // [B, 900]
    int B)
{
    __shared__ alignas(16) float stg[TFL];   // 57600 B single buffer

    const int t    = threadIdx.x;
    const int lane = t & 63;
    const int wid  = t >> 6;

    const int brow = lane & 15;             // D col (n) -> b-row within tile
    const int k0   = (lane >> 4) << 3;      // fragment k offset
    const int dloc = (lane >> 4) << 2;      // D row (m) base -> d offset in chunk
    const long long b0 = (long long)blockIdx.x * RPB;

    // ---- prologue 1: issue ALL sc loads (8 tiles x 2 float4 per lane) ----
    float4 ra[TILES], rb[TILES];
    #pragma unroll
    for (int tt = 0; tt < TILES; ++tt) {
        const float* ap = sc + (size_t)(b0 + tt * TROWS + brow) * KD + k0;
        ra[tt] = *reinterpret_cast<const float4*>(ap);
        rb[tt] = *reinterpret_cast<const float4*>(ap + 4);
    }

    // ---- prologue 2: dict fragments df[15]: wave wid owns chunks wid+4j ----
    // A-fragment layout: m = lane&15 (-> d within chunk), k = (lane>>4)*8 + j.
    bf16x8 df[15];
    #pragma unroll
    for (int j = 0; j < 15; ++j) {
        int ch = wid + 4 * j; if (ch > NCHT - 1) ch = NCHT - 1;   // dup, unused
        int d  = ch * 16 + (lane & 15);
        int dd = (d < DDIM) ? d : (DDIM - 1);                     // pad lanes
        const float* p = dict + (size_t)serp_src(dd) * KD + k0;
        const float4 f0 = *reinterpret_cast<const float4*>(p);
        const float4 f1 = *reinterpret_cast<const float4*>(p + 4);
        bf16x8 a;
        a[0] = f2bf(f0.x); a[1] = f2bf(f0.y); a[2] = f2bf(f0.z); a[3] = f2bf(f0.w);
        a[4] = f2bf(f1.x); a[5] = f2bf(f1.y); a[6] = f2bf(f1.z); a[7] = f2bf(f1.w);
        df[j] = a;
    }

    // ---- prologue 3: convert sc fragments to bf16 (statically indexed) ----
    bf16x8 bb[TILES];
    #pragma unroll
    for (int tt = 0; tt < TILES; ++tt) {
        bf16x8 r;
        r[0] = f2bf(ra[tt].x); r[1] = f2bf(ra[tt].y);
        r[2] = f2bf(ra[tt].z); r[3] = f2bf(ra[tt].w);
        r[4] = f2bf(rb[tt].x); r[5] = f2bf(rb[tt].y);
        r[6] = f2bf(rb[tt].z); r[7] = f2bf(rb[tt].w);
        bb[tt] = r;
    }

    const int base = t * 4;

    // ---- steady loop: NO vmem reads, NO vmcnt waits, fully unrolled ----
    #pragma unroll
    for (int tile = 0; tile < TILES; ++tile) {
        // compute tile into staging (MFMA + ds_write pipes)
        #pragma unroll
        for (int j = 0; j < 15; ++j) {
            const int ch = wid + 4 * j;
            if (ch < NCHT) {                         // wave-uniform
                f32x4 z = {0.f, 0.f, 0.f, 0.f};
                f32x4 acc = __builtin_amdgcn_mfma_f32_16x16x32_bf16(df[j], bb[tile], z, 0, 0, 0);
                if (ch != 56) {
                    *reinterpret_cast<f32x4*>(&stg[brow * DDIM + ch * 16 + dloc]) = acc;
                } else if (dloc == 0) {              // only d=896..899 valid
                    *reinterpret_cast<f32x4*>(&stg[brow * DDIM + 896]) = acc;
                }
            }
        }
        barrier_lds();   // staging visible; global stores stay in flight

        // copy tile: literal fill pattern, fully contiguous
        float* __restrict__ tbase = out + (size_t)(b0 + (long long)tile * TROWS) * DDIM;
        #pragma unroll
        for (int i = 0; i < 14; ++i) {
            const int o = i * 1024 + base;           // 14*1024 = 14336
            f32x4 v = *reinterpret_cast<const f32x4*>(&stg[o]);
            *reinterpret_cast<f32x4*>(tbase + o) = v;
        }
        if (t < 16) {                                // 14336 + 64 = 14400
            const int o = 14336 + base;
            f32x4 v = *reinterpret_cast<const f32x4*>(&stg[o]);
            *reinterpret_cast<f32x4*>(tbase + o) = v;
        }
        barrier_lds();   // staging reusable; stores stay in flight
    }
}

extern "C" void kernel_launch(void* const* d_in, const int* in_sizes, int n_in,
                              void* d_out, int out_size, void* d_ws, size_t ws_size,
                              hipStream_t stream) {
    const float* sc   = (const float*)d_in[0];   // [B, 32]
    const float* dict = (const float*)d_in[1];   // [900, 32]
    float* out        = (float*)d_out;           // [B, 1, 30, 30] flat = [B, 900]

    const int B = in_sizes[0] / KD;              // 262144 (divisible by RPB=128)

    mfma_decode<<<dim3((unsigned)(B / RPB)), 256, 0, stream>>>(sc, dict, out, B);
}

// Round 13
// 195.110 us; speedup vs baseline: 1.0320x; 1.0320x over previous
//
#include <hip/hip_runtime.h>
#include <hip/hip_bf16.h>

// out[b, d] = sum_k sc[b,k] * dict[serp(d), k]    B=262144, K=32, D=900.
//
// R9-R12 post-mortem: all scheduling variants land 194-203us (~4.8 TB/s vs
// 6.8 fill). R11 residual = ~2100 cyc/tile store-idle: the per-tile barrier
// re-syncs all 4 waves, which enter the compute section in LOCKSTEP -> a
// window every tile where no wave issues stores. Symmetric waves can't fix
// lockstep; role asymmetry can.
// R13: producer/consumer wave specialization. 512 threads, 1 block/CU:
// waves 0-3 produce (sc+dict in regs, MFMA, ds_write), waves 4-7 consume
// (ds_read -> global_store ONLY -- fill's loop verbatim, ~100% store duty).
// Double-buffer 2x57.6KB; ONE lgkm-only barrier/tile covers both hazards
// (producers wrote buf[(i+1)&1]; consumers done reading buf[i&1]). Copy
// (~5200 cyc backpressured) >> compute (~900) so producers always arrive
// at the barrier early; consumer store stream pauses only at the barrier.

typedef __attribute__((ext_vector_type(8))) short bf16x8;
typedef __attribute__((ext_vector_type(4))) float f32x4;

constexpr int KD    = 32;
constexpr int DDIM  = 900;
constexpr int SDIM  = 30;
constexpr int NCHT  = 57;              // 16-col chunks (57*16 = 912)
constexpr int TROWS = 16;              // rows per tile (= MFMA n)
constexpr int TILES = 16;              // tiles per block
constexpr int RPB   = TROWS * TILES;   // 256 rows per block -> 1024 blocks
constexpr int TFL   = TROWS * DDIM;    // 14400 floats per staging buffer

__device__ __forceinline__ int serp_src(int d) {
    int r = d / SDIM, c = d - r * SDIM;
    return (r & 1) ? (r * SDIM + (SDIM - 1 - c)) : d;
}

__device__ __forceinline__ short f2bf(float x) {
    __hip_bfloat16 h = __float2bfloat16(x);   // RNE
    short u; __builtin_memcpy(&u, &h, 2); return u;
}

// Barrier ordering LDS only: waits own ds ops, does NOT drain global stores.
__device__ __forceinline__ void barrier_lds() {
    __builtin_amdgcn_sched_barrier(0);
    asm volatile("s_waitcnt lgkmcnt(0)" ::: "memory");
    __builtin_amdgcn_sched_barrier(0);
    __builtin_amdgcn_s_barrier();
    __builtin_amdgcn_sched_barrier(0);
}

__global__ __launch_bounds__(512, 1) void mfma_decode(
    const float* __restrict__ sc,     // [B, 32]
    const float* __restrict__ dict,   // [900, 32]
    float* __restrict__ out,          // [B, 900]
    int B)
{
    __shared__ alignas(16) float stg[2][TFL];   // 115200 B double buffer

    const int t    = threadIdx.x;
    const int lane = t & 63;
    const int wid  = t >> 6;                    // 0..7

    const int brow = lane & 15;             // D col (n) -> b-row within tile
    const int k0   = (lane >> 4) << 3;      // fragment k offset
    const int dloc = (lane >> 4) << 2;      // D row (m) base -> d offset in chunk
    const long long b0 = (long long)blockIdx.x * RPB;

    bf16x8 df[15];
    bf16x8 bb[TILES];

    // MFMA pass for one tile -> staging buffer buf (producer waves only).
    auto compute = [&](const bf16x8& bbx, float* buf) {
        #pragma unroll
        for (int j = 0; j < 15; ++j) {
            const int ch = wid + 4 * j;          // wid in 0..3 here
            if (ch < NCHT) {                     // wave-uniform
                f32x4 z = {0.f, 0.f, 0.f, 0.f};
                f32x4 acc = __builtin_amdgcn_mfma_f32_16x16x32_bf16(df[j], bbx, z, 0, 0, 0);
                if (ch != 56) {
                    *reinterpret_cast<f32x4*>(&buf[brow * DDIM + ch * 16 + dloc]) = acc;
                } else if (dloc == 0) {          // only d=896..899 valid
                    *reinterpret_cast<f32x4*>(&buf[brow * DDIM + 896]) = acc;
                }
            }
        }
    };

    if (wid < 4) {
        // ---- producer prologue: dict fragments (chunks wid+4j) ----
        // A-fragment layout: m = lane&15 (d within chunk), k = (lane>>4)*8+j.
        #pragma unroll
        for (int j = 0; j < 15; ++j) {
            int ch = wid + 4 * j; if (ch > NCHT - 1) ch = NCHT - 1;
            int d  = ch * 16 + (lane & 15);
            int dd = (d < DDIM) ? d : (DDIM - 1);
            const float* p = dict + (size_t)serp_src(dd) * KD + k0;
            const float4 f0 = *reinterpret_cast<const float4*>(p);
            const float4 f1 = *reinterpret_cast<const float4*>(p + 4);
            bf16x8 a;
            a[0] = f2bf(f0.x); a[1] = f2bf(f0.y); a[2] = f2bf(f0.z); a[3] = f2bf(f0.w);
            a[4] = f2bf(f1.x); a[5] = f2bf(f1.y); a[6] = f2bf(f1.z); a[7] = f2bf(f1.w);
            df[j] = a;
        }

        // ---- sc fragments, 4 tiles per group (caps register liveness) ----
        #pragma unroll
        for (int g = 0; g < TILES / 4; ++g) {
            float4 ra[4], rb[4];
            #pragma unroll
            for (int u = 0; u < 4; ++u) {
                const int tt = g * 4 + u;
                const float* ap = sc + (size_t)(b0 + tt * TROWS + brow) * KD + k0;
                ra[u] = *reinterpret_cast<const float4*>(ap);
                rb[u] = *reinterpret_cast<const float4*>(ap + 4);
            }
            #pragma unroll
            for (int u = 0; u < 4; ++u) {
                bf16x8 r;
                r[0] = f2bf(ra[u].x); r[1] = f2bf(ra[u].y);
                r[2] = f2bf(ra[u].z); r[3] = f2bf(ra[u].w);
                r[4] = f2bf(rb[u].x); r[5] = f2bf(rb[u].y);
                r[6] = f2bf(rb[u].z); r[7] = f2bf(rb[u].w);
                bb[g * 4 + u] = r;
            }
        }

        compute(bb[0], stg[0]);
    }
    barrier_lds();   // buf0 ready; consumers were waiting here

    const int base = (t - 256) * 4;   // consumer copy offset (floats)

    #pragma unroll
    for (int tile = 0; tile < TILES; ++tile) {
        if (wid < 4) {
            // ---- producer: compute tile+1 into the other buffer ----
            if (tile + 1 < TILES) compute(bb[tile + 1], stg[(tile + 1) & 1]);
        } else {
            // ---- consumer: copy tile -> global; fill's loop verbatim ----
            const float* __restrict__ buf = stg[tile & 1];
            float* __restrict__ tbase =
                out + (size_t)(b0 + (long long)tile * TROWS) * DDIM;
            #pragma unroll
            for (int i = 0; i < 14; ++i) {
                const int o = i * 1024 + base;       // 14*1024 = 14336
                f32x4 v = *reinterpret_cast<const f32x4*>(&buf[o]);
                *reinterpret_cast<f32x4*>(tbase + o) = v;
            }
            if (t < 272) {                           // t-256 < 16: last 64 floats
                const int o = 14336 + base;
                f32x4 v = *reinterpret_cast<const f32x4*>(&buf[o]);
                *reinterpret_cast<f32x4*>(tbase + o) = v;
            }
        }
        barrier_lds();   // producer wrote buf[(tile+1)&1]; consumer read buf[tile&1]
    }                    // global stores stay in flight throughout
}

extern "C" void kernel_launch(void* const* d_in, const int* in_sizes, int n_in,
                              void* d_out, int out_size, void* d_ws, size_t ws_size,
                              hipStream_t stream) {
    const float* sc   = (const float*)d_in[0];   // [B, 32]
    const float* dict = (const float*)d_in[1];   // [900, 32]
    float* out        = (float*)d_out;           // [B, 1, 30, 30] flat = [B, 900]

    const int B = in_sizes[0] / KD;              // 262144 (divisible by RPB=256)

    mfma_decode<<<dim3((unsigned)(B / RPB)), 512, 0, stream>>>(sc, dict, out, B);
}